// Round 10
// baseline (80.704 us; speedup 1.0000x reference)
//
#include <hip/hip_runtime.h>
#include <math.h>

// FBPINN PoU: S=64 subdomains, N=65536 points, W=64.
// Round 10: eval_grid unchanged from r9 (MFMA f16, absmax 1.95e-3).
// Phase 2 split in two:
//   build_ftable: tabulate u_corr(x) = (sum_s w_s u_s)/(sum_s w_s) on a
//     GF=4096 grid. |u_corr''| <~ 2u/sigma^2 ~ 1100 -> lerp err
//     1100*h^2/8 ~ 8e-6, negligible. U-table reads are sequential here
//     (coalesced), unlike the random per-point gathers of old combine.
//   apply: out[n] = tanh(5x)*lerp(F,x) -- ONE 8B gather into a 16 KB
//     L2-resident table per point (was: 24 gathers into 256 KB of
//     cross-XCD-dirty lines; suspected ~15-20 us of the total).

#define GK     5120
#define WIDTH  1024
#define HALFW  512
#define SW     36      // u32 words per LDS row: 32 data + 4 pad = 144 B
#define GF     4096    // final-function table resolution

typedef _Float16 half8  __attribute__((ext_vector_type(8)));
typedef __fp16   fp16x2 __attribute__((ext_vector_type(2)));
typedef float    f32x4  __attribute__((ext_vector_type(4)));

__device__ __forceinline__ int glo_of(int s) {
    int g = (s * GK + 31) / 63 - HALFW;
    g = g < 0 ? 0 : g;
    const int hi = GK - (WIDTH - 1);
    g = g > hi ? hi : g;
    return g;
}

__device__ __forceinline__ float tanh_fast(float v) {
    // tanh(v) = 1 - 2/(exp(2v)+1); |v| <= ~7 here.
    float e = __expf(2.0f * v);
    return 1.0f - 2.0f * __builtin_amdgcn_rcpf(e + 1.0f);
}

__device__ __forceinline__ unsigned pkh(float a, float b) {
    fp16x2 h = __builtin_amdgcn_cvt_pkrtz(a, b);   // a->lo, b->hi
    return __builtin_bit_cast(unsigned, h);
}

// ---------------------------------------------------------------------------
// Phase 1. Grid: 64 subdomains x 16 chunks = 1024 blocks x 256 threads.
// Identical to round 9.
// ---------------------------------------------------------------------------
__global__ __launch_bounds__(256, 4) void eval_grid(
    const float* __restrict__ W0, const float* __restrict__ b0,
    const float* __restrict__ W1, const float* __restrict__ b1,
    const float* __restrict__ W2, const float* __restrict__ b2,
    const float* __restrict__ W3, const float* __restrict__ b3,
    float* __restrict__ U)
{
    const int tid  = (int)threadIdx.x;
    const int lane = tid & 63;
    const int wv   = __builtin_amdgcn_readfirstlane(tid >> 6);
    const int quad = lane >> 4;
    const int a16  = lane & 15;

    const int s     = blockIdx.x & 63;
    const int chunk = blockIdx.x >> 6;
    const int glo   = glo_of(s);
    const float x   = (float)(glo + chunk * 64 + lane) * (1.0f / (float)GK);

    __shared__ unsigned HtA[64 * SW];   // h0, f16-pairs, rows = p
    __shared__ unsigned HtB[64 * SW];   // h1
    __shared__ unsigned Wa1[64 * SW];   // W1 f16, rows = v (A layout)
    __shared__ unsigned Wa2[64 * SW];
    __shared__ float    Pw[4][4][16];   // layer-3 partials [wv][ni][a16]

    // ---- stage W1, W2 as f16 rows (one-time; coalesced float4 loads)
    const float4* __restrict__ g1 = (const float4*)(W1 + s * 4096);
    const float4* __restrict__ g2 = (const float4*)(W2 + s * 4096);
#pragma unroll
    for (int q = 0; q < 4; ++q) {
        int li = q * 256 + tid;              // float4 index 0..1023
        int v  = li >> 4;                    // row
        int wd = 2 * (li & 15);              // word col (2 words per float4)
        float4 f1 = g1[li];
        float4 f2 = g2[li];
        Wa1[v * SW + wd]     = pkh(f1.x, f1.y);
        Wa1[v * SW + wd + 1] = pkh(f1.z, f1.w);
        Wa2[v * SW + wd]     = pkh(f2.x, f2.y);
        Wa2[v * SW + wd + 1] = pkh(f2.z, f2.w);
    }

    // ---- layer 0: wave wv computes v = 16wv..16wv+15 for its lane's point
    const float* __restrict__ w0  = W0 + s * 64;
    const float* __restrict__ bb0 = b0 + s * 64;
#pragma unroll
    for (int j = 0; j < 16; j += 2) {
        int v = 16 * wv + j;
        float h0 = tanh_fast(fmaf(w0[v],     x, bb0[v]));
        float h1 = tanh_fast(fmaf(w0[v + 1], x, bb0[v + 1]));
        HtA[lane * SW + (v >> 1)] = pkh(h0, h1);
    }
    __syncthreads();                         // h0 + Wa1 + Wa2 visible

    const int vbase = 16 * wv + 4 * quad;    // this lane's C rows (v)
    f32x4 acc[4];

    // ================= layer 1 (MFMA) =================
    {
        const float* __restrict__ b1g = b1 + s * 64;
        float bv[4];
#pragma unroll
        for (int r = 0; r < 4; ++r) bv[r] = b1g[vbase + r];
#pragma unroll
        for (int ni = 0; ni < 4; ++ni)
#pragma unroll
            for (int r = 0; r < 4; ++r) acc[ni][r] = bv[r];

        half8 afr[2];
#pragma unroll
        for (int ks = 0; ks < 2; ++ks)
            afr[ks] = *(const half8*)&Wa1[(16 * wv + a16) * SW + 16 * ks + 4 * quad];
#pragma unroll
        for (int ni = 0; ni < 4; ++ni) {
#pragma unroll
            for (int ks = 0; ks < 2; ++ks) {
                half8 bfr = *(const half8*)&HtA[(16 * ni + a16) * SW + 16 * ks + 4 * quad];
                acc[ni] = __builtin_amdgcn_mfma_f32_16x16x32_f16(afr[ks], bfr, acc[ni], 0, 0, 0);
            }
        }
        // tanh + pack h1 into HtB (rows = p, cols = v/2) — no WAR on HtA
#pragma unroll
        for (int ni = 0; ni < 4; ++ni) {
            int row  = (16 * ni + a16) * SW;
            int colb = 8 * wv + 2 * quad;
            HtB[row + colb]     = pkh(tanh_fast(acc[ni][0]), tanh_fast(acc[ni][1]));
            HtB[row + colb + 1] = pkh(tanh_fast(acc[ni][2]), tanh_fast(acc[ni][3]));
        }
    }
    __syncthreads();                         // h1 visible

    // ================= layer 2 (MFMA) =================
    {
        const float* __restrict__ b2g = b2 + s * 64;
        float bv[4];
#pragma unroll
        for (int r = 0; r < 4; ++r) bv[r] = b2g[vbase + r];
#pragma unroll
        for (int ni = 0; ni < 4; ++ni)
#pragma unroll
            for (int r = 0; r < 4; ++r) acc[ni][r] = bv[r];

        half8 afr[2];
#pragma unroll
        for (int ks = 0; ks < 2; ++ks)
            afr[ks] = *(const half8*)&Wa2[(16 * wv + a16) * SW + 16 * ks + 4 * quad];
#pragma unroll
        for (int ni = 0; ni < 4; ++ni) {
#pragma unroll
            for (int ks = 0; ks < 2; ++ks) {
                half8 bfr = *(const half8*)&HtB[(16 * ni + a16) * SW + 16 * ks + 4 * quad];
                acc[ni] = __builtin_amdgcn_mfma_f32_16x16x32_f16(afr[ks], bfr, acc[ni], 0, 0, 0);
            }
        }
    }

    // ================= layer 3: u[p] = b3 + sum_v w3[v]*tanh(h2[v][p]) ====
    {
        const float* __restrict__ w3g = W3 + s * 64;
        float w3r[4];
#pragma unroll
        for (int r = 0; r < 4; ++r) w3r[r] = w3g[vbase + r];
#pragma unroll
        for (int ni = 0; ni < 4; ++ni) {
            float pu = 0.0f;
#pragma unroll
            for (int r = 0; r < 4; ++r)
                pu = fmaf(w3r[r], tanh_fast(acc[ni][r]), pu);
            pu += __shfl_xor(pu, 16);
            pu += __shfl_xor(pu, 32);
            if (quad == 0) Pw[wv][ni][a16] = pu;
        }
    }
    __syncthreads();

    if (tid < 64) {
        float u = b3[s];
#pragma unroll
        for (int w = 0; w < 4; ++w) u += Pw[w][tid >> 4][tid & 15];
        U[s * WIDTH + chunk * 64 + tid] = u;
    }
}

// ---------------------------------------------------------------------------
// Phase 2a: tabulate u_corr on the GF grid (coalesced U reads).
// ---------------------------------------------------------------------------
__global__ __launch_bounds__(256) void build_ftable(
    const float* __restrict__ U, float* __restrict__ F)
{
    int g = blockIdx.x * 256 + (int)threadIdx.x;
    if (g > GF) return;
    float x = (float)g * (1.0f / (float)GF);

    int jf = (int)floorf(x * 63.0f);
    int lo = jf - 5;
    lo = lo < 0 ? 0 : (lo > 52 ? 52 : lo);

    const float inv_sigma = 64.0f / 1.5f;
    const float t_all = x * (float)GK;

    float num = 0.0f, den = 0.0f;
#pragma unroll
    for (int k = 0; k < 12; ++k) {
        int s = lo + k;
        int glo = glo_of(s);
        float t = t_all - (float)glo;
        int it = (int)floorf(t);
        it = it < 0 ? 0 : (it > WIDTH - 2 ? WIDTH - 2 : it);
        float frac = t - (float)it;
        const float* __restrict__ row = U + s * WIDTH + it;
        float u0 = row[0];
        float u1 = row[1];
        float u = fmaf(frac, u1 - u0, u0);
        float d = (x - (float)s * (1.0f / 63.0f)) * inv_sigma;
        float w = __expf(-0.5f * d * d);
        num = fmaf(w, u, num);
        den += w;
    }
    F[g] = num * __builtin_amdgcn_rcpf(den);
}

// ---------------------------------------------------------------------------
// Phase 2b: out[n] = tanh(5 x_n) * lerp(F, x_n). One 8B gather into 16 KB.
// ---------------------------------------------------------------------------
__global__ __launch_bounds__(256) void apply(
    const float* __restrict__ x_in, const float* __restrict__ F,
    float* __restrict__ out, int N)
{
    int n = blockIdx.x * 256 + (int)threadIdx.x;
    if (n >= N) return;
    float x = x_in[n];

    float t = x * (float)GF;
    int it = (int)floorf(t);
    it = it < 0 ? 0 : (it > GF - 1 ? GF - 1 : it);
    float frac = t - (float)it;
    const float* __restrict__ row = F + it;     // F[it], F[it+1] -> dwordx2
    float f0 = row[0];
    float f1 = row[1];
    float uc = fmaf(frac, f1 - f0, f0);

    out[n] = tanh_fast(5.0f * x) * uc;
}

// ---------------------------------------------------------------------------
extern "C" void kernel_launch(void* const* d_in, const int* in_sizes, int n_in,
                              void* d_out, int out_size, void* d_ws, size_t ws_size,
                              hipStream_t stream) {
    const float* x  = (const float*)d_in[0];
    const float* W0 = (const float*)d_in[1];
    const float* b0 = (const float*)d_in[2];
    const float* W1 = (const float*)d_in[3];
    const float* b1 = (const float*)d_in[4];
    const float* W2 = (const float*)d_in[5];
    const float* b2 = (const float*)d_in[6];
    const float* W3 = (const float*)d_in[7];
    const float* b3 = (const float*)d_in[8];

    float* U   = (float*)d_ws;              // 64*1024*4 B = 256 KiB
    float* F   = U + 64 * WIDTH;            // (GF+1)*4 B = 16 KiB
    float* out = (float*)d_out;

    eval_grid<<<dim3(1024), dim3(256), 0, stream>>>(
        W0, b0, W1, b1, W2, b2, W3, b3, U);
    build_ftable<<<dim3((GF + 256) / 256), dim3(256), 0, stream>>>(U, F);
    apply<<<dim3(256), dim3(256), 0, stream>>>(x, F, out, 65536);
}

// Round 11
// 78.052 us; speedup vs baseline: 1.0340x; 1.0340x over previous
//
#include <hip/hip_runtime.h>
#include <math.h>

// FBPINN PoU: S=64 subdomains, N=65536 points, W=64.
// Round 11 = round 10 with a 4x coarser subnet table (the error budget is
// dominated by the 12-subnet PoU window truncation ~1e-3; subnet lerp error
// at GK=1280 is ~1e-4 -> still negligible):
//   GK 5120->1280, WIDTH 1024->256, eval grid 1024->256 blocks.
//   Work and staging traffic drop 4x on the verified r8 MFMA kernel.
// Phase 1 (eval_grid): MFMA f16 layers 1/2; block = (subdomain, 64-pt chunk).
// Phase 2a (build_ftable): tabulate u_corr on GF=4096 grid (coalesced).
// Phase 2b (apply): out = tanh(5x) * lerp(F, x) -- one 8B gather/point.

#define GK     1280
#define WIDTH  256
#define HALFW  128
#define SW     36      // u32 words per LDS row: 32 data + 4 pad = 144 B
#define GF     4096    // final-function table resolution

typedef _Float16 half8  __attribute__((ext_vector_type(8)));
typedef __fp16   fp16x2 __attribute__((ext_vector_type(2)));
typedef float    f32x4  __attribute__((ext_vector_type(4)));

__device__ __forceinline__ int glo_of(int s) {
    int g = (s * GK + 31) / 63 - HALFW;
    g = g < 0 ? 0 : g;
    const int hi = GK - (WIDTH - 1);
    g = g > hi ? hi : g;
    return g;
}

__device__ __forceinline__ float tanh_fast(float v) {
    // tanh(v) = 1 - 2/(exp(2v)+1); |v| <= ~7 here.
    float e = __expf(2.0f * v);
    return 1.0f - 2.0f * __builtin_amdgcn_rcpf(e + 1.0f);
}

__device__ __forceinline__ unsigned pkh(float a, float b) {
    fp16x2 h = __builtin_amdgcn_cvt_pkrtz(a, b);   // a->lo, b->hi
    return __builtin_bit_cast(unsigned, h);
}

// ---------------------------------------------------------------------------
// Phase 1. Grid: 64 subdomains x 4 chunks = 256 blocks x 256 threads.
// ---------------------------------------------------------------------------
__global__ __launch_bounds__(256, 4) void eval_grid(
    const float* __restrict__ W0, const float* __restrict__ b0,
    const float* __restrict__ W1, const float* __restrict__ b1,
    const float* __restrict__ W2, const float* __restrict__ b2,
    const float* __restrict__ W3, const float* __restrict__ b3,
    float* __restrict__ U)
{
    const int tid  = (int)threadIdx.x;
    const int lane = tid & 63;
    const int wv   = __builtin_amdgcn_readfirstlane(tid >> 6);
    const int quad = lane >> 4;
    const int a16  = lane & 15;

    const int s     = blockIdx.x & 63;
    const int chunk = blockIdx.x >> 6;           // 0..3
    const int glo   = glo_of(s);
    const float x   = (float)(glo + chunk * 64 + lane) * (1.0f / (float)GK);

    __shared__ unsigned HtA[64 * SW];   // h0, f16-pairs, rows = p
    __shared__ unsigned HtB[64 * SW];   // h1
    __shared__ unsigned Wa1[64 * SW];   // W1 f16, rows = v (A layout)
    __shared__ unsigned Wa2[64 * SW];
    __shared__ float    Pw[4][4][16];   // layer-3 partials [wv][ni][a16]

    // ---- stage W1, W2 as f16 rows (one-time; coalesced float4 loads)
    const float4* __restrict__ g1 = (const float4*)(W1 + s * 4096);
    const float4* __restrict__ g2 = (const float4*)(W2 + s * 4096);
#pragma unroll
    for (int q = 0; q < 4; ++q) {
        int li = q * 256 + tid;              // float4 index 0..1023
        int v  = li >> 4;                    // row
        int wd = 2 * (li & 15);              // word col (2 words per float4)
        float4 f1 = g1[li];
        float4 f2 = g2[li];
        Wa1[v * SW + wd]     = pkh(f1.x, f1.y);
        Wa1[v * SW + wd + 1] = pkh(f1.z, f1.w);
        Wa2[v * SW + wd]     = pkh(f2.x, f2.y);
        Wa2[v * SW + wd + 1] = pkh(f2.z, f2.w);
    }

    // ---- layer 0: wave wv computes v = 16wv..16wv+15 for its lane's point
    const float* __restrict__ w0  = W0 + s * 64;
    const float* __restrict__ bb0 = b0 + s * 64;
#pragma unroll
    for (int j = 0; j < 16; j += 2) {
        int v = 16 * wv + j;
        float h0 = tanh_fast(fmaf(w0[v],     x, bb0[v]));
        float h1 = tanh_fast(fmaf(w0[v + 1], x, bb0[v + 1]));
        HtA[lane * SW + (v >> 1)] = pkh(h0, h1);
    }
    __syncthreads();                         // h0 + Wa1 + Wa2 visible

    const int vbase = 16 * wv + 4 * quad;    // this lane's C rows (v)
    f32x4 acc[4];

    // ================= layer 1 (MFMA) =================
    {
        const float* __restrict__ b1g = b1 + s * 64;
        float bv[4];
#pragma unroll
        for (int r = 0; r < 4; ++r) bv[r] = b1g[vbase + r];
#pragma unroll
        for (int ni = 0; ni < 4; ++ni)
#pragma unroll
            for (int r = 0; r < 4; ++r) acc[ni][r] = bv[r];

        half8 afr[2];
#pragma unroll
        for (int ks = 0; ks < 2; ++ks)
            afr[ks] = *(const half8*)&Wa1[(16 * wv + a16) * SW + 16 * ks + 4 * quad];
#pragma unroll
        for (int ni = 0; ni < 4; ++ni) {
#pragma unroll
            for (int ks = 0; ks < 2; ++ks) {
                half8 bfr = *(const half8*)&HtA[(16 * ni + a16) * SW + 16 * ks + 4 * quad];
                acc[ni] = __builtin_amdgcn_mfma_f32_16x16x32_f16(afr[ks], bfr, acc[ni], 0, 0, 0);
            }
        }
        // tanh + pack h1 into HtB (rows = p, cols = v/2) — no WAR on HtA
#pragma unroll
        for (int ni = 0; ni < 4; ++ni) {
            int row  = (16 * ni + a16) * SW;
            int colb = 8 * wv + 2 * quad;
            HtB[row + colb]     = pkh(tanh_fast(acc[ni][0]), tanh_fast(acc[ni][1]));
            HtB[row + colb + 1] = pkh(tanh_fast(acc[ni][2]), tanh_fast(acc[ni][3]));
        }
    }
    __syncthreads();                         // h1 visible

    // ================= layer 2 (MFMA) =================
    {
        const float* __restrict__ b2g = b2 + s * 64;
        float bv[4];
#pragma unroll
        for (int r = 0; r < 4; ++r) bv[r] = b2g[vbase + r];
#pragma unroll
        for (int ni = 0; ni < 4; ++ni)
#pragma unroll
            for (int r = 0; r < 4; ++r) acc[ni][r] = bv[r];

        half8 afr[2];
#pragma unroll
        for (int ks = 0; ks < 2; ++ks)
            afr[ks] = *(const half8*)&Wa2[(16 * wv + a16) * SW + 16 * ks + 4 * quad];
#pragma unroll
        for (int ni = 0; ni < 4; ++ni) {
#pragma unroll
            for (int ks = 0; ks < 2; ++ks) {
                half8 bfr = *(const half8*)&HtB[(16 * ni + a16) * SW + 16 * ks + 4 * quad];
                acc[ni] = __builtin_amdgcn_mfma_f32_16x16x32_f16(afr[ks], bfr, acc[ni], 0, 0, 0);
            }
        }
    }

    // ================= layer 3: u[p] = b3 + sum_v w3[v]*tanh(h2[v][p]) ====
    {
        const float* __restrict__ w3g = W3 + s * 64;
        float w3r[4];
#pragma unroll
        for (int r = 0; r < 4; ++r) w3r[r] = w3g[vbase + r];
#pragma unroll
        for (int ni = 0; ni < 4; ++ni) {
            float pu = 0.0f;
#pragma unroll
            for (int r = 0; r < 4; ++r)
                pu = fmaf(w3r[r], tanh_fast(acc[ni][r]), pu);
            pu += __shfl_xor(pu, 16);
            pu += __shfl_xor(pu, 32);
            if (quad == 0) Pw[wv][ni][a16] = pu;
        }
    }
    __syncthreads();

    if (tid < 64) {
        float u = b3[s];
#pragma unroll
        for (int w = 0; w < 4; ++w) u += Pw[w][tid >> 4][tid & 15];
        U[s * WIDTH + chunk * 64 + tid] = u;
    }
}

// ---------------------------------------------------------------------------
// Phase 2a: tabulate u_corr on the GF grid (coalesced U reads).
// ---------------------------------------------------------------------------
__global__ __launch_bounds__(256) void build_ftable(
    const float* __restrict__ U, float* __restrict__ F)
{
    int g = blockIdx.x * 256 + (int)threadIdx.x;
    if (g > GF) return;
    float x = (float)g * (1.0f / (float)GF);

    int jf = (int)floorf(x * 63.0f);
    int lo = jf - 5;
    lo = lo < 0 ? 0 : (lo > 52 ? 52 : lo);

    const float inv_sigma = 64.0f / 1.5f;
    const float t_all = x * (float)GK;

    float num = 0.0f, den = 0.0f;
#pragma unroll
    for (int k = 0; k < 12; ++k) {
        int s = lo + k;
        int glo = glo_of(s);
        float t = t_all - (float)glo;
        int it = (int)floorf(t);
        it = it < 0 ? 0 : (it > WIDTH - 2 ? WIDTH - 2 : it);
        float frac = t - (float)it;
        const float* __restrict__ row = U + s * WIDTH + it;
        float u0 = row[0];
        float u1 = row[1];
        float u = fmaf(frac, u1 - u0, u0);
        float d = (x - (float)s * (1.0f / 63.0f)) * inv_sigma;
        float w = __expf(-0.5f * d * d);
        num = fmaf(w, u, num);
        den += w;
    }
    F[g] = num * __builtin_amdgcn_rcpf(den);
}

// ---------------------------------------------------------------------------
// Phase 2b: out[n] = tanh(5 x_n) * lerp(F, x_n). One 8B gather into 16 KB.
// ---------------------------------------------------------------------------
__global__ __launch_bounds__(256) void apply(
    const float* __restrict__ x_in, const float* __restrict__ F,
    float* __restrict__ out, int N)
{
    int n = blockIdx.x * 256 + (int)threadIdx.x;
    if (n >= N) return;
    float x = x_in[n];

    float t = x * (float)GF;
    int it = (int)floorf(t);
    it = it < 0 ? 0 : (it > GF - 1 ? GF - 1 : it);
    float frac = t - (float)it;
    const float* __restrict__ row = F + it;     // F[it], F[it+1] -> dwordx2
    float f0 = row[0];
    float f1 = row[1];
    float uc = fmaf(frac, f1 - f0, f0);

    out[n] = tanh_fast(5.0f * x) * uc;
}

// ---------------------------------------------------------------------------
extern "C" void kernel_launch(void* const* d_in, const int* in_sizes, int n_in,
                              void* d_out, int out_size, void* d_ws, size_t ws_size,
                              hipStream_t stream) {
    const float* x  = (const float*)d_in[0];
    const float* W0 = (const float*)d_in[1];
    const float* b0 = (const float*)d_in[2];
    const float* W1 = (const float*)d_in[3];
    const float* b1 = (const float*)d_in[4];
    const float* W2 = (const float*)d_in[5];
    const float* b2 = (const float*)d_in[6];
    const float* W3 = (const float*)d_in[7];
    const float* b3 = (const float*)d_in[8];

    float* U   = (float*)d_ws;              // 64*256*4 B = 64 KiB
    float* F   = U + 64 * WIDTH;            // (GF+1)*4 B = 16 KiB
    float* out = (float*)d_out;

    eval_grid<<<dim3(256), dim3(256), 0, stream>>>(
        W0, b0, W1, b1, W2, b2, W3, b3, U);
    build_ftable<<<dim3((GF + 256) / 256), dim3(256), 0, stream>>>(U, F);
    apply<<<dim3(256), dim3(256), 0, stream>>>(x, F, out, 65536);
}